// Round 2
// baseline (577.085 us; speedup 1.0000x reference)
//
#include <hip/hip_runtime.h>
#include <hip/hip_bf16.h>
#include <stdint.h>

#define DM 1024   // d_model
#define DD 512    // d (head dim / proj out)
#define BB 32     // batch
#define LL 1024   // seq len
#define SCALE 0.04419417382415922f  // 1/sqrt(512)

typedef float f32x4 __attribute__((ext_vector_type(4)));
typedef short bf16x8 __attribute__((ext_vector_type(8)));
typedef short bf16x4 __attribute__((ext_vector_type(4)));

__device__ inline unsigned short f2bf(float f) {
    union { float f; uint32_t u; } v; v.f = f;
    uint32_t r = v.u + 0x7fffu + ((v.u >> 16) & 1u);
    return (unsigned short)(r >> 16);
}

__device__ inline bf16x4 cvt4(f32x4 a, float s) {
    bf16x4 r;
    r[0] = (short)f2bf(a[0] * s);
    r[1] = (short)f2bf(a[1] * s);
    r[2] = (short)f2bf(a[2] * s);
    r[3] = (short)f2bf(a[3] * s);
    return r;
}

#define GLOAD_LDS16(gsrc, ldst) \
    __builtin_amdgcn_global_load_lds((const __attribute__((address_space(1))) unsigned int*)(gsrc), \
        (__attribute__((address_space(3))) unsigned int*)(ldst), 16, 0, 0)

// ---------------------------------------------------------------------------
// Kernel 1: q/k/v projection (UNCHANGED from round 0 — passed, 566 TF-class).
// ---------------------------------------------------------------------------
__global__ __launch_bounds__(256) void qkv_proj(
    const float* __restrict__ x,
    const float* __restrict__ Wq, const float* __restrict__ bq,
    const float* __restrict__ Wk, const float* __restrict__ bk,
    const float* __restrict__ Wv, const float* __restrict__ bv,
    unsigned short* __restrict__ qkv)
{
    __shared__ __align__(16) unsigned short At[128][40];
    __shared__ __align__(16) unsigned short Bt[128][40];

    const int o = blockIdx.y;  // 0=q 1=k 2=v
    const float* W    = (o == 0) ? Wq : (o == 1) ? Wk : Wv;
    const float* bias = (o == 0) ? bq : (o == 1) ? bk : bv;
    const float wscale = (o == 0) ? SCALE : 1.0f;
    unsigned short* out = qkv + (size_t)o * (size_t)(BB * LL) * DD;

    int wg = blockIdx.x;
    wg = (wg & 7) * 128 + (wg >> 3);
    const int rowbase = (wg >> 2) * 128;
    const int colbase = (wg & 3) * 128;

    const int tid  = threadIdx.x;
    const int lane = tid & 63;
    const int w    = tid >> 6;
    const int wr   = (w >> 1) * 64;
    const int wc   = (w & 1) * 64;

    f32x4 acc[4][4];
    #pragma unroll
    for (int i = 0; i < 4; ++i)
        #pragma unroll
        for (int j = 0; j < 4; ++j)
            acc[i][j] = (f32x4){0.f, 0.f, 0.f, 0.f};

    for (int kk = 0; kk < DM; kk += 32) {
        const float* xs = x + (size_t)rowbase * DM + kk;
        const float* wp = W + (size_t)colbase * DM + kk;
        #pragma unroll
        for (int i = 0; i < 4; ++i) {
            int c = tid + i * 256;
            int r = c >> 3;
            int f = (c & 7) * 4;
            f32x4 xv = *(const f32x4*)(xs + (size_t)r * DM + f);
            *(bf16x4*)&At[r][f] = cvt4(xv, 1.0f);
            f32x4 wv = *(const f32x4*)(wp + (size_t)r * DM + f);
            *(bf16x4*)&Bt[r][f] = cvt4(wv, wscale);
        }
        __syncthreads();

        bf16x8 af[4], bfr[4];
        #pragma unroll
        for (int m = 0; m < 4; ++m)
            af[m] = *(const bf16x8*)&At[wr + m * 16 + (lane & 15)][(lane >> 4) * 8];
        #pragma unroll
        for (int n = 0; n < 4; ++n)
            bfr[n] = *(const bf16x8*)&Bt[wc + n * 16 + (lane & 15)][(lane >> 4) * 8];
        #pragma unroll
        for (int n = 0; n < 4; ++n)
            #pragma unroll
            for (int m = 0; m < 4; ++m)
                acc[m][n] = __builtin_amdgcn_mfma_f32_16x16x32_bf16(af[m], bfr[n], acc[m][n], 0, 0, 0);
        __syncthreads();
    }

    #pragma unroll
    for (int n = 0; n < 4; ++n) {
        int col = colbase + wc + n * 16 + (lane & 15);
        float bv_ = bias[col] * wscale;
        #pragma unroll
        for (int m = 0; m < 4; ++m) {
            int row0 = rowbase + wr + m * 16 + (lane >> 4) * 4;
            #pragma unroll
            for (int r = 0; r < 4; ++r)
                out[(size_t)(row0 + r) * DD + col] = f2bf(acc[m][n][r] + bv_);
        }
    }
}

// ---------------------------------------------------------------------------
// Kernel 2: V transpose.  v[b][l][d] (bf16) -> vt[b][d][l] (bf16).
// 64x64 LDS tiles; HBM-bound (~64 MB total traffic).
// ---------------------------------------------------------------------------
__global__ __launch_bounds__(256) void vtrans(const unsigned short* __restrict__ v,
                                              unsigned short* __restrict__ vt)
{
    __shared__ unsigned short T[64][72];   // 144B row stride (8B aligned writes)
    const int lt = blockIdx.x, dt = blockIdx.y, b = blockIdx.z;
    const int t = threadIdx.x;
    const unsigned short* src = v + ((size_t)(b * LL + lt * 64)) * DD + dt * 64;
    #pragma unroll
    for (int it = 0; it < 2; ++it) {
        int r  = (t >> 3) + it * 32;
        int c0 = (t & 7) * 8;
        bf16x8 x = *(const bf16x8*)(src + (size_t)r * DD + c0);
        *(bf16x4*)&T[r][c0]     = (bf16x4){x[0], x[1], x[2], x[3]};
        *(bf16x4*)&T[r][c0 + 4] = (bf16x4){x[4], x[5], x[6], x[7]};
    }
    __syncthreads();
    unsigned short* dst = vt + ((size_t)(b * DD + dt * 64)) * LL + lt * 64;
    #pragma unroll
    for (int it = 0; it < 2; ++it) {
        int d  = (t >> 3) + it * 32;
        int c0 = (t & 7) * 8;
        bf16x8 o;
        #pragma unroll
        for (int e = 0; e < 8; ++e) o[e] = T[c0 + e][d];
        *(bf16x8*)(dst + (size_t)d * LL + c0) = o;
    }
}

// ---------------------------------------------------------------------------
// Kernel 3: flash attention v2.
// Block = (b, 64-row q-tile), 256 threads = 4 waves; wave w owns q-rows
// [qt*64+w*16, +16) end-to-end (no cross-wave S reduction).
// K tile [64][512] staged linear in LDS via global_load_lds with XOR bank
// swizzle (pre-swizzled global src + swizzled ds_read — both-sides rule).
// V fragments read directly from pre-transposed Vt (global/L2).
// Per-wave P in padded LDS (no barrier). Online softmax in registers with
// deferred-max rescale. Staging of tile t+1 overlaps softmax+PV of tile t.
// ---------------------------------------------------------------------------
__global__ __launch_bounds__(256, 2) void attn2(
    const unsigned short* __restrict__ qkv,
    const unsigned short* __restrict__ vt,
    const int* __restrict__ mask,
    float* __restrict__ outp)
{
    __shared__ __align__(16) unsigned short KtL[32768];   // 64 KB, [64 rows][1024 B]
    __shared__ __align__(16) unsigned short Pw[4][16][80]; // 10,240 B
    __shared__ float bias[1024];                           // 4 KB
    // total 79,872 B -> 2 blocks/CU

    const int bx = blockIdx.x;
    const int h = bx >> 8, i = bx & 255;
    const int b = i & 31;
    const int qtx = (i >> 5) & 7;
    const int qt = h ? qtx : 15 - qtx;   // balanced pairing: CU gets qt & 15-qt

    const int tid = threadIdx.x, lane = tid & 63, w = tid >> 6;
    const int l15 = lane & 15, l4 = lane >> 4;

    const unsigned short* q = qkv;
    const unsigned short* k = qkv + (size_t)(BB * LL) * DD;

    // stage mask->bias once
    {
        const int* mp = mask + b * LL;
        #pragma unroll
        for (int j = 0; j < 4; ++j)
            bias[tid * 4 + j] = mp[tid * 4 + j] ? 0.0f : -1e30f;
    }

    // persistent Q A-frags (16 x bf16x8 = 64 VGPR)
    bf16x8 qf[16];
    {
        const unsigned short* qp = q + ((size_t)(b * LL + qt * 64 + w * 16 + l15)) * DD + l4 * 8;
        #pragma unroll
        for (int ks = 0; ks < 16; ++ks)
            qf[ks] = *(const bf16x8*)(qp + ks * 32);
    }

    f32x4 oacc[32];
    #pragma unroll
    for (int n = 0; n < 32; ++n) oacc[n] = (f32x4){0.f, 0.f, 0.f, 0.f};
    float mrow[4] = {-1e30f, -1e30f, -1e30f, -1e30f};
    float lrow[4] = {0.f, 0.f, 0.f, 0.f};

    const char* kb = (const char*)k + ((size_t)b * LL) * DD * 2;  // K[b], row = 1024 B
    const int lsw = lane * 16;

    // prologue: stage tile 0
    {
        const char* ktile = kb;
        #pragma unroll
        for (int i2 = 0; i2 < 16; ++i2) {
            int row = i2 * 4 + w;
            GLOAD_LDS16(ktile + (row << 10) + (lsw ^ ((row & 7) << 4)),
                        (char*)KtL + (row << 10));
        }
    }

    const int swz = (l15 & 7) << 4;

    for (int jt = 0; jt <= qt; ++jt) {
        __syncthreads();   // stage(jt) drained (syncthreads implies vmcnt(0)) + bias visible

        // ---- QK^T: S[16 own rows][64 keys], K from swizzled LDS ----
        f32x4 sacc[4];
        #pragma unroll
        for (int nf = 0; nf < 4; ++nf) sacc[nf] = (f32x4){0.f, 0.f, 0.f, 0.f};
        #pragma unroll
        for (int ks = 0; ks < 16; ++ks) {
            #pragma unroll
            for (int nf = 0; nf < 4; ++nf) {
                int coloff = ((ks << 6) + (l4 << 4)) ^ swz;
                const bf16x8 kf = *(const bf16x8*)((const char*)KtL
                                    + (((nf * 16 + l15)) << 10) + coloff);
                sacc[nf] = __builtin_amdgcn_mfma_f32_16x16x32_bf16(qf[ks], kf, sacc[nf], 0, 0, 0);
            }
        }
        __syncthreads();   // Kt fully consumed by all waves

        // ---- overlap: issue stage(jt+1) now; completes during softmax+PV ----
        if (jt < qt) {
            const char* ktile = kb + ((size_t)(jt + 1) << 16);  // (jt+1)*64 rows * 1024 B
            #pragma unroll
            for (int i2 = 0; i2 < 16; ++i2) {
                int row = i2 * 4 + w;
                GLOAD_LDS16(ktile + (row << 10) + (lsw ^ ((row & 7) << 4)),
                            (char*)KtL + (row << 10));
            }
        }

        // ---- mask + causal + online softmax (in-register, per 16-lane row group) ----
        const bool diag = (jt == qt);
        float s[4][4];
        #pragma unroll
        for (int nf = 0; nf < 4; ++nf) {
            float bb_ = bias[jt * 64 + nf * 16 + l15];
            #pragma unroll
            for (int r = 0; r < 4; ++r) {
                float val = sacc[nf][r] + bb_;
                if (diag) {
                    int gi = w * 16 + l4 * 4 + r;
                    int gj = nf * 16 + l15;
                    val = (gj <= gi) ? val : -1e30f;
                }
                s[nf][r] = val;
            }
        }
        float pm[4];
        #pragma unroll
        for (int r = 0; r < 4; ++r) {
            float mx = fmaxf(fmaxf(s[0][r], s[1][r]), fmaxf(s[2][r], s[3][r]));
            mx = fmaxf(mx, __shfl_xor(mx, 1));
            mx = fmaxf(mx, __shfl_xor(mx, 2));
            mx = fmaxf(mx, __shfl_xor(mx, 4));
            mx = fmaxf(mx, __shfl_xor(mx, 8));
            pm[r] = mx;
        }
        bool need = false;
        #pragma unroll
        for (int r = 0; r < 4; ++r) need |= (pm[r] - mrow[r] > 8.0f);
        if (need) {   // deferred-max: uniform across each 16-lane row group
            #pragma unroll
            for (int r = 0; r < 4; ++r) {
                float mn = fmaxf(mrow[r], pm[r]);
                float corr = __expf(mrow[r] - mn);
                mrow[r] = mn;
                lrow[r] *= corr;
                #pragma unroll
                for (int n = 0; n < 32; ++n) oacc[n][r] *= corr;
            }
        }
        #pragma unroll
        for (int r = 0; r < 4; ++r) {
            float ls = 0.f;
            #pragma unroll
            for (int nf = 0; nf < 4; ++nf) {
                float p = __expf(s[nf][r] - mrow[r]);
                ls += p;
                Pw[w][l4 * 4 + r][nf * 16 + l15] = f2bf(p);
            }
            ls += __shfl_xor(ls, 1);
            ls += __shfl_xor(ls, 2);
            ls += __shfl_xor(ls, 4);
            ls += __shfl_xor(ls, 8);
            lrow[r] += ls;
        }

        // ---- PV: O[16 own rows][512] += P[16][64] * V[64][512], V from global Vt ----
        const bf16x8 pa0 = *(const bf16x8*)&Pw[w][l15][l4 * 8];
        const bf16x8 pa1 = *(const bf16x8*)&Pw[w][l15][32 + l4 * 8];
        const unsigned short* vb = vt + ((size_t)(b * DD + l15)) * LL + jt * 64 + l4 * 8;
        #pragma unroll
        for (int n = 0; n < 32; ++n) {
            bf16x8 v0 = *(const bf16x8*)(vb + (size_t)n * 16 * LL);
            bf16x8 v1 = *(const bf16x8*)(vb + (size_t)n * 16 * LL + 32);
            oacc[n] = __builtin_amdgcn_mfma_f32_16x16x32_bf16(pa0, v0, oacc[n], 0, 0, 0);
            oacc[n] = __builtin_amdgcn_mfma_f32_16x16x32_bf16(pa1, v1, oacc[n], 0, 0, 0);
        }
    }

    // ---- epilogue: relu(O / l) ----
    float inv[4];
    #pragma unroll
    for (int r = 0; r < 4; ++r) inv[r] = 1.0f / lrow[r];
    float* op = outp + ((size_t)(b * LL + qt * 64 + w * 16 + l4 * 4)) * DD + l15;
    #pragma unroll
    for (int n = 0; n < 32; ++n)
        #pragma unroll
        for (int r = 0; r < 4; ++r)
            op[(size_t)r * DD + n * 16] = fmaxf(oacc[n][r] * inv[r], 0.f);
}

extern "C" void kernel_launch(void* const* d_in, const int* in_sizes, int n_in,
                              void* d_out, int out_size, void* d_ws, size_t ws_size,
                              hipStream_t stream) {
    const float* x  = (const float*)d_in[0];
    const float* Wq = (const float*)d_in[1];
    const float* bq = (const float*)d_in[2];
    const float* Wk = (const float*)d_in[3];
    const float* bk = (const float*)d_in[4];
    const float* Wv = (const float*)d_in[5];
    const float* bv = (const float*)d_in[6];
    const int* mask = (const int*)d_in[7];

    unsigned short* qkv = (unsigned short*)d_ws;                 // q|k|v, each 16M elems
    unsigned short* v   = qkv + (size_t)2 * (BB * LL) * DD;
    unsigned short* vtp = qkv + (size_t)3 * (BB * LL) * DD;      // vt: [B][D][L]
    float* out = (float*)d_out;

    qkv_proj<<<dim3(1024, 3), 256, 0, stream>>>(x, Wq, bq, Wk, bk, Wv, bv, qkv);
    vtrans<<<dim3(16, 8, 32), 256, 0, stream>>>(v, vtp);
    attn2<<<dim3(512), 256, 0, stream>>>(qkv, vtp, mask, out);
}

// Round 3
// 333.293 us; speedup vs baseline: 1.7315x; 1.7315x over previous
//
#include <hip/hip_runtime.h>
#include <hip/hip_bf16.h>
#include <stdint.h>

#define DM 1024   // d_model
#define DD 512    // d (proj out / head dim)
#define BB 32     // batch
#define LL 1024   // seq len
#define SCALE 0.04419417382415922f  // 1/sqrt(512)
#define MAT ((size_t)BB * LL * DD)  // 16,777,216 elems per q/k/v matrix

typedef float f32x4 __attribute__((ext_vector_type(4)));
typedef short bf16x8 __attribute__((ext_vector_type(8)));
typedef short bf16x4 __attribute__((ext_vector_type(4)));

__device__ inline unsigned short f2bf(float f) {
    union { float f; uint32_t u; } v; v.f = f;
    uint32_t r = v.u + 0x7fffu + ((v.u >> 16) & 1u);
    return (unsigned short)(r >> 16);
}

__device__ inline bf16x4 cvt4(f32x4 a, float s) {
    bf16x4 r;
    r[0] = (short)f2bf(a[0] * s);
    r[1] = (short)f2bf(a[1] * s);
    r[2] = (short)f2bf(a[2] * s);
    r[3] = (short)f2bf(a[3] * s);
    return r;
}

#define GLOAD_LDS16(gsrc, ldst) \
    __builtin_amdgcn_global_load_lds((const __attribute__((address_space(1))) unsigned int*)(gsrc), \
        (__attribute__((address_space(3))) unsigned int*)(ldst), 16, 0, 0)

// ---------------------------------------------------------------------------
// Kernel 0a: cast x fp32 -> bf16 (dest: d_out reused as scratch; dead by attn)
// ---------------------------------------------------------------------------
__global__ __launch_bounds__(256) void cast_x(const float* __restrict__ x,
                                              unsigned short* __restrict__ xb)
{
    size_t idx = (size_t)blockIdx.x * 256 + threadIdx.x;
    size_t base = idx * 8;
    f32x4 a = *(const f32x4*)(x + base);
    f32x4 b = *(const f32x4*)(x + base + 4);
    bf16x4 lo = cvt4(a, 1.0f), hi = cvt4(b, 1.0f);
    bf16x8 o = {lo[0], lo[1], lo[2], lo[3], hi[0], hi[1], hi[2], hi[3]};
    *(bf16x8*)(xb + base) = o;
}

// ---------------------------------------------------------------------------
// Kernel 0b: cast Wq/Wk/Wv fp32 -> bf16 (Wq pre-scaled by 1/sqrt(D))
// ---------------------------------------------------------------------------
__global__ __launch_bounds__(256) void cast_w(const float* __restrict__ Wq,
                                              const float* __restrict__ Wk,
                                              const float* __restrict__ Wv,
                                              unsigned short* __restrict__ Wb)
{
    size_t idx = (size_t)blockIdx.x * 256 + threadIdx.x;   // 0..196607
    int o = (int)(idx >> 16);                               // 65536 chunks per matrix
    size_t rem = idx & 65535;
    const float* W = (o == 0) ? Wq : (o == 1) ? Wk : Wv;
    float s = (o == 0) ? SCALE : 1.0f;
    size_t base = rem * 8;
    f32x4 a = *(const f32x4*)(W + base);
    f32x4 b = *(const f32x4*)(W + base + 4);
    bf16x4 lo = cvt4(a, s), hi = cvt4(b, s);
    bf16x8 out = {lo[0], lo[1], lo[2], lo[3], hi[0], hi[1], hi[2], hi[3]};
    *(bf16x8*)(Wb + (size_t)o * 524288 + base) = out;
}

// ---------------------------------------------------------------------------
// Kernel 1: q/k/v projection, pure-bf16 inputs (no per-iter conversion).
// 128x128 tile, BK=32, 4 waves; reg-staged bf16x8 loads into padded LDS.
// ---------------------------------------------------------------------------
__global__ __launch_bounds__(256) void qkv_proj2(
    const unsigned short* __restrict__ xb,   // [32768][1024] bf16
    const unsigned short* __restrict__ Wb,   // [3][512][1024] bf16 (q pre-scaled)
    const float* __restrict__ bq, const float* __restrict__ bk, const float* __restrict__ bv,
    unsigned short* __restrict__ qkv)
{
    __shared__ __align__(16) unsigned short At[128][40];
    __shared__ __align__(16) unsigned short Bt[128][40];

    const int o = blockIdx.y;
    const float* bias = (o == 0) ? bq : (o == 1) ? bk : bv;
    const float wscale = (o == 0) ? SCALE : 1.0f;
    const unsigned short* W = Wb + (size_t)o * 524288;
    unsigned short* out = qkv + (size_t)o * MAT;

    int wg = blockIdx.x;
    wg = (wg & 7) * 128 + (wg >> 3);
    const int rowbase = (wg >> 2) * 128;
    const int colbase = (wg & 3) * 128;

    const int tid  = threadIdx.x;
    const int lane = tid & 63;
    const int w    = tid >> 6;
    const int wr   = (w >> 1) * 64;
    const int wc   = (w & 1) * 64;

    f32x4 acc[4][4];
    #pragma unroll
    for (int i = 0; i < 4; ++i)
        #pragma unroll
        for (int j = 0; j < 4; ++j)
            acc[i][j] = (f32x4){0.f, 0.f, 0.f, 0.f};

    for (int kk = 0; kk < DM; kk += 32) {
        const unsigned short* xs = xb + (size_t)rowbase * DM + kk;
        const unsigned short* wp = W + (size_t)colbase * DM + kk;
        #pragma unroll
        for (int i = 0; i < 2; ++i) {
            int c = tid + i * 256;        // 512 chunks: 128 rows x 4 x 16B
            int r = c >> 2;
            int q = (c & 3) * 8;
            *(bf16x8*)&At[r][q] = *(const bf16x8*)(xs + (size_t)r * DM + q);
            *(bf16x8*)&Bt[r][q] = *(const bf16x8*)(wp + (size_t)r * DM + q);
        }
        __syncthreads();

        bf16x8 af[4], bfr[4];
        #pragma unroll
        for (int m = 0; m < 4; ++m)
            af[m] = *(const bf16x8*)&At[wr + m * 16 + (lane & 15)][(lane >> 4) * 8];
        #pragma unroll
        for (int n = 0; n < 4; ++n)
            bfr[n] = *(const bf16x8*)&Bt[wc + n * 16 + (lane & 15)][(lane >> 4) * 8];
        #pragma unroll
        for (int n = 0; n < 4; ++n)
            #pragma unroll
            for (int m = 0; m < 4; ++m)
                acc[m][n] = __builtin_amdgcn_mfma_f32_16x16x32_bf16(af[m], bfr[n], acc[m][n], 0, 0, 0);
        __syncthreads();
    }

    #pragma unroll
    for (int n = 0; n < 4; ++n) {
        int col = colbase + wc + n * 16 + (lane & 15);
        float bv_ = bias[col] * wscale;
        #pragma unroll
        for (int m = 0; m < 4; ++m) {
            int row0 = rowbase + wr + m * 16 + (lane >> 4) * 4;
            #pragma unroll
            for (int r = 0; r < 4; ++r)
                out[(size_t)(row0 + r) * DD + col] = f2bf(acc[m][n][r] + bv_);
        }
    }
}

// ---------------------------------------------------------------------------
// Kernel 2: V transpose.  v[b][l][d] -> vt[b][d][l]  (bf16)
// ---------------------------------------------------------------------------
__global__ __launch_bounds__(256) void vtrans(const unsigned short* __restrict__ v,
                                              unsigned short* __restrict__ vt)
{
    __shared__ unsigned short T[64][72];
    const int lt = blockIdx.x, dt = blockIdx.y, b = blockIdx.z;
    const int t = threadIdx.x;
    const unsigned short* src = v + ((size_t)(b * LL + lt * 64)) * DD + dt * 64;
    #pragma unroll
    for (int it = 0; it < 2; ++it) {
        int r  = (t >> 3) + it * 32;
        int c0 = (t & 7) * 8;
        bf16x8 x = *(const bf16x8*)(src + (size_t)r * DD + c0);
        *(bf16x4*)&T[r][c0]     = (bf16x4){x[0], x[1], x[2], x[3]};
        *(bf16x4*)&T[r][c0 + 4] = (bf16x4){x[4], x[5], x[6], x[7]};
    }
    __syncthreads();
    unsigned short* dst = vt + ((size_t)(b * DD + dt * 64)) * LL + lt * 64;
    #pragma unroll
    for (int it = 0; it < 2; ++it) {
        int d  = (t >> 3) + it * 32;
        int c0 = (t & 7) * 8;
        bf16x8 o;
        #pragma unroll
        for (int e = 0; e < 8; ++e) o[e] = T[c0 + e][d];
        *(bf16x8*)(dst + (size_t)d * LL + c0) = o;
    }
}

// ---------------------------------------------------------------------------
// Kernel 3: flash attention v3.
// Block = (b, 64-row q-tile), 4 waves; wave owns 16 q-rows end-to-end.
// KVBLK=32. K and V tiles DOUBLE-BUFFERED in LDS, staged via global_load_lds
// (K: XOR-swizzled source + swizzled read; V: from pre-transposed vt, linear
// [512][32] whose b128 reads are uniformly 8-way = free). One raw barrier +
// vmcnt(0) per tile; stage(jt+1) issued before compute(jt) => fully hidden.
// ---------------------------------------------------------------------------
__device__ inline void tile_barrier() {
    asm volatile("s_waitcnt vmcnt(0)" ::: "memory");
    __builtin_amdgcn_sched_barrier(0);
    __builtin_amdgcn_s_barrier();
    __builtin_amdgcn_sched_barrier(0);
}

__global__ __launch_bounds__(256, 1) void attn3(
    const unsigned short* __restrict__ qkv,
    const unsigned short* __restrict__ vt,
    const int* __restrict__ mask,
    float* __restrict__ outp)
{
    __shared__ __align__(16) unsigned short KtL[2][16384];  // 2 x [32 keys][512 d] = 64 KB
    __shared__ __align__(16) unsigned short VtL[2][16384];  // 2 x [512 d][32 keys] = 64 KB
    __shared__ __align__(16) unsigned short Pw[4][16][36];  // 4.5 KB
    __shared__ float mbias[1024];                           // 4 KB; total 139,776 B

    const int bx = blockIdx.x;
    const int h = bx >> 8, i = bx & 255;
    const int b = i & 31;
    const int qtx = (i >> 5) & 7;
    const int qt = h ? qtx : 15 - qtx;   // pair heavy+light tiles per CU round

    const int tid = threadIdx.x, lane = tid & 63, w = tid >> 6;
    const int l15 = lane & 15, l4 = lane >> 4;
    const int lsw = lane * 16;

    const unsigned short* q = qkv;
    const unsigned short* k = qkv + MAT;
    const char* kb  = (const char*)k + ((size_t)b * LL) * DD * 2;   // K[b], row=1024B
    const char* vtb = (const char*)vt + ((size_t)b * DD) * LL * 2;  // Vt[b], row=2048B

    // mask -> additive bias
    {
        const int* mp = mask + b * LL;
        #pragma unroll
        for (int j = 0; j < 4; ++j)
            mbias[tid * 4 + j] = mp[tid * 4 + j] ? 0.0f : -1e30f;
    }

    // persistent Q A-frags (64 VGPR)
    bf16x8 qf[16];
    {
        const unsigned short* qp = q + ((size_t)(b * LL + qt * 64 + w * 16 + l15)) * DD + l4 * 8;
        #pragma unroll
        for (int ks = 0; ks < 16; ++ks)
            qf[ks] = *(const bf16x8*)(qp + ks * 32);
    }

    f32x4 oacc[32];
    #pragma unroll
    for (int n = 0; n < 32; ++n) oacc[n] = (f32x4){0.f, 0.f, 0.f, 0.f};
    float mrow[4] = {-1e30f, -1e30f, -1e30f, -1e30f};
    float lrow[4] = {0.f, 0.f, 0.f, 0.f};

    const int jtmax = 2 * qt + 1;

    // ---- stage(tile, buf): K 8 instrs + V 8 instrs per wave ----
    #define STAGE_KV(JT, BUF) do {                                              \
        const char* kt = kb + ((size_t)(JT) << 15);                             \
        char* ldsK = (char*)&KtL[(BUF)][0];                                     \
        _Pragma("unroll")                                                       \
        for (int i2 = 0; i2 < 8; ++i2) {                                        \
            int row = i2 * 4 + w;                                               \
            GLOAD_LDS16(kt + (row << 10) + (lsw ^ ((row & 7) << 4)),            \
                        ldsK + (row << 10));                                    \
        }                                                                       \
        const char* vtj = vtb + ((size_t)(JT) << 6);                            \
        char* ldsV = (char*)&VtL[(BUF)][0];                                     \
        _Pragma("unroll")                                                       \
        for (int i2 = 0; i2 < 8; ++i2) {                                        \
            int c0 = i2 * 256 + w * 64;                                         \
            int c  = c0 + lane;                                                 \
            GLOAD_LDS16(vtj + ((size_t)(c >> 2) << 11) + ((c & 3) << 4),        \
                        ldsV + c0 * 16);                                        \
        }                                                                       \
    } while (0)

    STAGE_KV(0, 0);
    __syncthreads();   // stage(0) + mbias visible

    const int swz = (l15 & 7) << 4;

    for (int jt = 0; jt <= jtmax; ++jt) {
        const int cur = jt & 1;
        if (jt < jtmax) STAGE_KV(jt + 1, cur ^ 1);

        // ---- QK^T: S[16 own rows][32 keys] from swizzled K LDS ----
        const char* Kc = (const char*)&KtL[cur][0];
        f32x4 sacc[2];
        sacc[0] = (f32x4){0.f, 0.f, 0.f, 0.f};
        sacc[1] = (f32x4){0.f, 0.f, 0.f, 0.f};
        #pragma unroll
        for (int ks = 0; ks < 16; ++ks) {
            int coloff = ((ks << 6) + (l4 << 4)) ^ swz;
            #pragma unroll
            for (int nf = 0; nf < 2; ++nf) {
                const bf16x8 kf = *(const bf16x8*)(Kc + ((nf * 16 + l15) << 10) + coloff);
                sacc[nf] = __builtin_amdgcn_mfma_f32_16x16x32_bf16(qf[ks], kf, sacc[nf], 0, 0, 0);
            }
        }

        // ---- mask + causal + online softmax (in-register) ----
        const bool diag = (jt >= 2 * qt);
        float s[2][4];
        #pragma unroll
        for (int nf = 0; nf < 2; ++nf) {
            float bb_ = mbias[jt * 32 + nf * 16 + l15];
            #pragma unroll
            for (int r = 0; r < 4; ++r) {
                float val = sacc[nf][r] + bb_;
                if (diag) {
                    int gi = qt * 64 + w * 16 + l4 * 4 + r;
                    int gj = jt * 32 + nf * 16 + l15;
                    val = (gj <= gi) ? val : -3e38f;
                }
                s[nf][r] = val;
            }
        }
        float pm[4];
        #pragma unroll
        for (int r = 0; r < 4; ++r) {
            float mx = fmaxf(s[0][r], s[1][r]);
            mx = fmaxf(mx, __shfl_xor(mx, 1));
            mx = fmaxf(mx, __shfl_xor(mx, 2));
            mx = fmaxf(mx, __shfl_xor(mx, 4));
            mx = fmaxf(mx, __shfl_xor(mx, 8));
            pm[r] = mx;
        }
        bool need = false;
        #pragma unroll
        for (int r = 0; r < 4; ++r) need |= (pm[r] - mrow[r] > 8.0f);
        if (__any(need)) {   // wave-uniform; corr==1 for untouched groups
            #pragma unroll
            for (int r = 0; r < 4; ++r) {
                float mn = fmaxf(mrow[r], pm[r]);
                float corr = __expf(mrow[r] - mn);
                mrow[r] = mn;
                lrow[r] *= corr;
                #pragma unroll
                for (int n = 0; n < 32; ++n) oacc[n][r] *= corr;
            }
        }
        #pragma unroll
        for (int r = 0; r < 4; ++r) {
            float ls = 0.f;
            #pragma unroll
            for (int nf = 0; nf < 2; ++nf) {
                float p = __expf(s[nf][r] - mrow[r]);
                ls += p;
                Pw[w][l4 * 4 + r][nf * 16 + l15] = f2bf(p);
            }
            ls += __shfl_xor(ls, 1);
            ls += __shfl_xor(ls, 2);
            ls += __shfl_xor(ls, 4);
            ls += __shfl_xor(ls, 8);
            lrow[r] += ls;
        }

        // ---- PV: O[16 rows][512] += P[16][32] * V[32][512] (V from LDS) ----
        const bf16x8 pa = *(const bf16x8*)&Pw[w][l15][l4 * 8];
        const char* Vc = (const char*)&VtL[cur][0];
        #pragma unroll
        for (int n = 0; n < 32; ++n) {
            const bf16x8 vb_ = *(const bf16x8*)(Vc + ((n * 16 + l15) << 6) + (l4 << 4));
            oacc[n] = __builtin_amdgcn_mfma_f32_16x16x32_bf16(pa, vb_, oacc[n], 0, 0, 0);
        }

        if (jt < jtmax) tile_barrier();   // stage(jt+1) drained; all waves done with buf[cur]
    }

    // ---- epilogue: relu(O / l) ----
    float inv[4];
    #pragma unroll
    for (int r = 0; r < 4; ++r) inv[r] = 1.0f / lrow[r];
    float* op = outp + ((size_t)(b * LL + qt * 64 + w * 16 + l4 * 4)) * DD + l15;
    #pragma unroll
    for (int n = 0; n < 32; ++n)
        #pragma unroll
        for (int r = 0; r < 4; ++r)
            op[(size_t)r * DD + n * 16] = fmaxf(oacc[n][r] * inv[r], 0.f);
    #undef STAGE_KV
}

extern "C" void kernel_launch(void* const* d_in, const int* in_sizes, int n_in,
                              void* d_out, int out_size, void* d_ws, size_t ws_size,
                              hipStream_t stream) {
    const float* x  = (const float*)d_in[0];
    const float* Wq = (const float*)d_in[1];
    const float* bq = (const float*)d_in[2];
    const float* Wk = (const float*)d_in[3];
    const float* bk = (const float*)d_in[4];
    const float* Wv = (const float*)d_in[5];
    const float* bv = (const float*)d_in[6];
    const int* mask = (const int*)d_in[7];

    unsigned short* qkv = (unsigned short*)d_ws;          // q|k|v bf16, 3*MAT elems
    unsigned short* v   = qkv + 2 * MAT;
    unsigned short* vtp = qkv + 3 * MAT;                  // vt region (33.5 MB)
    unsigned short* Wb  = vtp;                            // Wb parked in vt region (3 MB),
                                                          // overwritten by vtrans afterwards
    unsigned short* xb  = (unsigned short*)d_out;         // x bf16 scratch (exactly fits);
                                                          // dead before attn3 writes output
    float* out = (float*)d_out;

    cast_x<<<16384, 256, 0, stream>>>(x, xb);
    cast_w<<<768, 256, 0, stream>>>(Wq, Wk, Wv, Wb);
    qkv_proj2<<<dim3(1024, 3), 256, 0, stream>>>(xb, Wb, bq, bk, bv, qkv);
    vtrans<<<dim3(16, 8, 32), 256, 0, stream>>>(v, vtp);
    attn3<<<dim3(512), 256, 0, stream>>>(qkv, vtp, mask, out);
}

// Round 4
// 290.841 us; speedup vs baseline: 1.9842x; 1.1460x over previous
//
#include <hip/hip_runtime.h>
#include <hip/hip_bf16.h>
#include <stdint.h>

#define DM 1024   // d_model
#define DD 512    // d (proj out / head dim)
#define BB 32     // batch
#define LL 1024   // seq len
#define SCALE 0.04419417382415922f  // 1/sqrt(512)
#define MAT ((size_t)BB * LL * DD)  // elems per q/k/v matrix

typedef float f32x4 __attribute__((ext_vector_type(4)));
typedef short bf16x8 __attribute__((ext_vector_type(8)));
typedef short bf16x4 __attribute__((ext_vector_type(4)));

__device__ inline unsigned short f2bf(float f) {
    union { float f; uint32_t u; } v; v.f = f;
    uint32_t r = v.u + 0x7fffu + ((v.u >> 16) & 1u);
    return (unsigned short)(r >> 16);
}

__device__ inline bf16x4 cvt4(f32x4 a, float s) {
    bf16x4 r;
    r[0] = (short)f2bf(a[0] * s);
    r[1] = (short)f2bf(a[1] * s);
    r[2] = (short)f2bf(a[2] * s);
    r[3] = (short)f2bf(a[3] * s);
    return r;
}

#define GLOAD_LDS16(gsrc, ldst) \
    __builtin_amdgcn_global_load_lds((const __attribute__((address_space(1))) unsigned int*)(gsrc), \
        (__attribute__((address_space(3))) unsigned int*)(ldst), 16, 0, 0)

__device__ inline void tile_barrier() {
    asm volatile("s_waitcnt vmcnt(0)" ::: "memory");
    __builtin_amdgcn_sched_barrier(0);
    __builtin_amdgcn_s_barrier();
    __builtin_amdgcn_sched_barrier(0);
}

// ---------------------------------------------------------------------------
// Kernel 0a: cast x fp32 -> bf16 (dest: d_out reused as scratch; dead by attn)
// ---------------------------------------------------------------------------
__global__ __launch_bounds__(256) void cast_x(const float* __restrict__ x,
                                              unsigned short* __restrict__ xb)
{
    size_t idx = (size_t)blockIdx.x * 256 + threadIdx.x;
    size_t base = idx * 8;
    f32x4 a = *(const f32x4*)(x + base);
    f32x4 b = *(const f32x4*)(x + base + 4);
    bf16x4 lo = cvt4(a, 1.0f), hi = cvt4(b, 1.0f);
    bf16x8 o = {lo[0], lo[1], lo[2], lo[3], hi[0], hi[1], hi[2], hi[3]};
    *(bf16x8*)(xb + base) = o;
}

// ---------------------------------------------------------------------------
// Kernel 0b: cast Wq/Wk/Wv fp32 -> bf16 (Wq pre-scaled by 1/sqrt(D))
// ---------------------------------------------------------------------------
__global__ __launch_bounds__(256) void cast_w(const float* __restrict__ Wq,
                                              const float* __restrict__ Wk,
                                              const float* __restrict__ Wv,
                                              unsigned short* __restrict__ Wb)
{
    size_t idx = (size_t)blockIdx.x * 256 + threadIdx.x;   // 0..196607
    int o = (int)(idx >> 16);
    size_t rem = idx & 65535;
    const float* W = (o == 0) ? Wq : (o == 1) ? Wk : Wv;
    float s = (o == 0) ? SCALE : 1.0f;
    size_t base = rem * 8;
    f32x4 a = *(const f32x4*)(W + base);
    f32x4 b = *(const f32x4*)(W + base + 4);
    bf16x4 lo = cvt4(a, s), hi = cvt4(b, s);
    bf16x8 out = {lo[0], lo[1], lo[2], lo[3], hi[0], hi[1], hi[2], hi[3]};
    *(bf16x8*)(Wb + (size_t)o * 524288 + base) = out;
}

// ---------------------------------------------------------------------------
// Kernel 1: q/k/v projection v3.
// 128x128 tile, BK=64, double-buffered LDS, staged via global_load_lds w16
// with both-sides XOR swizzle (pre-swizzled global src + chunk^(row&7) on
// ds_read_b128 -> 2-way banks = free). One vmcnt(0)+barrier per K-tile;
// stage(t+1) overlaps compute(t).
// ---------------------------------------------------------------------------
__global__ __launch_bounds__(256, 2) void qkv_proj3(
    const unsigned short* __restrict__ xb,   // [32768][1024] bf16
    const unsigned short* __restrict__ Wb,   // [3][512][1024] bf16 (q pre-scaled)
    const float* __restrict__ bq, const float* __restrict__ bk, const float* __restrict__ bv,
    unsigned short* __restrict__ qkv)
{
    __shared__ __align__(16) unsigned short At[2][8192];  // [buf][128 rows][128 B]
    __shared__ __align__(16) unsigned short Bt[2][8192];  // 64 KB total

    const int o = blockIdx.y;
    const float* bias = (o == 0) ? bq : (o == 1) ? bk : bv;
    const float wscale = (o == 0) ? SCALE : 1.0f;
    const unsigned short* W = Wb + (size_t)o * 524288;
    unsigned short* out = qkv + (size_t)o * MAT;

    int wg = blockIdx.x;
    wg = (wg & 7) * 128 + (wg >> 3);           // XCD swizzle (bijective, 1024 = 8*128)
    const int rowbase = (wg >> 2) * 128;
    const int colbase = (wg & 3) * 128;

    const int tid  = threadIdx.x;
    const int lane = tid & 63;
    const int w    = tid >> 6;
    const int wr   = (w >> 1) * 64;
    const int wc   = (w & 1) * 64;
    const int l15  = lane & 15, l4 = lane >> 4;

    // staging lane decomposition: 8 rows x 8 chunks(16B) per wave-instr
    const int r8   = lane >> 3;                // row within 8-row group
    const int swch = (lane & 7) ^ r8;          // pre-swizzled source chunk

    const char* xpanel = (const char*)(xb + (size_t)rowbase * DM);
    const char* wpanel = (const char*)(W  + (size_t)colbase * DM);

    f32x4 acc[4][4];
    #pragma unroll
    for (int i = 0; i < 4; ++i)
        #pragma unroll
        for (int j = 0; j < 4; ++j)
            acc[i][j] = (f32x4){0.f, 0.f, 0.f, 0.f};

    // stage(KK elems, BUF): A 4 instrs + B 4 instrs per wave (16 KB each tile)
    #define STAGE_AB(KK, BUF) do {                                               \
        _Pragma("unroll")                                                        \
        for (int i2 = 0; i2 < 4; ++i2) {                                         \
            int grp = i2 * 4 + w;             /* 8-row group, wave-uniform */    \
            size_t rowoff = (size_t)(grp * 8 + r8) * 2048 + (KK) * 2 + swch * 16;\
            GLOAD_LDS16(xpanel + rowoff, (char*)&At[BUF][0] + grp * 1024);       \
            GLOAD_LDS16(wpanel + rowoff, (char*)&Bt[BUF][0] + grp * 1024);       \
        }                                                                        \
    } while (0)

    STAGE_AB(0, 0);
    __syncthreads();

    for (int t = 0; t < 16; ++t) {
        const int cur = t & 1;
        if (t < 15) STAGE_AB((t + 1) * 64, cur ^ 1);

        const char* Ab = (const char*)&At[cur][0];
        const char* Bb = (const char*)&Bt[cur][0];
        #pragma unroll
        for (int ks = 0; ks < 2; ++ks) {
            bf16x8 af[4], bf_[4];
            const int ch = (ks * 4 + l4) ^ (l15 & 7);   // row&7 == l15&7 here
            #pragma unroll
            for (int m = 0; m < 4; ++m) {
                int row = wr + m * 16 + l15;
                af[m] = *(const bf16x8*)(Ab + row * 128 + (ch << 4));
            }
            #pragma unroll
            for (int n = 0; n < 4; ++n) {
                int row = wc + n * 16 + l15;
                bf_[n] = *(const bf16x8*)(Bb + row * 128 + (ch << 4));
            }
            #pragma unroll
            for (int n = 0; n < 4; ++n)
                #pragma unroll
                for (int m = 0; m < 4; ++m)
                    acc[m][n] = __builtin_amdgcn_mfma_f32_16x16x32_bf16(af[m], bf_[n], acc[m][n], 0, 0, 0);
        }

        if (t < 15) tile_barrier();
    }
    #undef STAGE_AB

    #pragma unroll
    for (int n = 0; n < 4; ++n) {
        int col = colbase + wc + n * 16 + l15;
        float bv_ = bias[col] * wscale;
        #pragma unroll
        for (int m = 0; m < 4; ++m) {
            int row0 = rowbase + wr + m * 16 + l4 * 4;
            #pragma unroll
            for (int r = 0; r < 4; ++r)
                out[(size_t)(row0 + r) * DD + col] = f2bf(acc[m][n][r] + bv_);
        }
    }
}

// ---------------------------------------------------------------------------
// Kernel 2: V transpose.  v[b][l][d] -> vt[b][d][l]  (bf16)
// ---------------------------------------------------------------------------
__global__ __launch_bounds__(256) void vtrans(const unsigned short* __restrict__ v,
                                              unsigned short* __restrict__ vt)
{
    __shared__ unsigned short T[64][72];
    const int lt = blockIdx.x, dt = blockIdx.y, b = blockIdx.z;
    const int t = threadIdx.x;
    const unsigned short* src = v + ((size_t)(b * LL + lt * 64)) * DD + dt * 64;
    #pragma unroll
    for (int it = 0; it < 2; ++it) {
        int r  = (t >> 3) + it * 32;
        int c0 = (t & 7) * 8;
        bf16x8 x = *(const bf16x8*)(src + (size_t)r * DD + c0);
        *(bf16x4*)&T[r][c0]     = (bf16x4){x[0], x[1], x[2], x[3]};
        *(bf16x4*)&T[r][c0 + 4] = (bf16x4){x[4], x[5], x[6], x[7]};
    }
    __syncthreads();
    unsigned short* dst = vt + ((size_t)(b * DD + dt * 64)) * LL + lt * 64;
    #pragma unroll
    for (int it = 0; it < 2; ++it) {
        int d  = (t >> 3) + it * 32;
        int c0 = (t & 7) * 8;
        bf16x8 o;
        #pragma unroll
        for (int e = 0; e < 8; ++e) o[e] = T[c0 + e][d];
        *(bf16x8*)(dst + (size_t)d * LL + c0) = o;
    }
}

// ---------------------------------------------------------------------------
// Kernel 3: flash attention v3 (unchanged from round 3).
// ---------------------------------------------------------------------------
__global__ __launch_bounds__(256, 1) void attn3(
    const unsigned short* __restrict__ qkv,
    const unsigned short* __restrict__ vt,
    const int* __restrict__ mask,
    float* __restrict__ outp)
{
    __shared__ __align__(16) unsigned short KtL[2][16384];  // 2 x [32 keys][512 d]
    __shared__ __align__(16) unsigned short VtL[2][16384];  // 2 x [512 d][32 keys]
    __shared__ __align__(16) unsigned short Pw[4][16][36];
    __shared__ float mbias[1024];

    const int bx = blockIdx.x;
    const int h = bx >> 8, i = bx & 255;
    const int b = i & 31;
    const int qtx = (i >> 5) & 7;
    const int qt = h ? qtx : 15 - qtx;

    const int tid = threadIdx.x, lane = tid & 63, w = tid >> 6;
    const int l15 = lane & 15, l4 = lane >> 4;
    const int lsw = lane * 16;

    const unsigned short* q = qkv;
    const unsigned short* k = qkv + MAT;
    const char* kb  = (const char*)k + ((size_t)b * LL) * DD * 2;
    const char* vtb = (const char*)vt + ((size_t)b * DD) * LL * 2;

    {
        const int* mp = mask + b * LL;
        #pragma unroll
        for (int j = 0; j < 4; ++j)
            mbias[tid * 4 + j] = mp[tid * 4 + j] ? 0.0f : -1e30f;
    }

    bf16x8 qf[16];
    {
        const unsigned short* qp = q + ((size_t)(b * LL + qt * 64 + w * 16 + l15)) * DD + l4 * 8;
        #pragma unroll
        for (int ks = 0; ks < 16; ++ks)
            qf[ks] = *(const bf16x8*)(qp + ks * 32);
    }

    f32x4 oacc[32];
    #pragma unroll
    for (int n = 0; n < 32; ++n) oacc[n] = (f32x4){0.f, 0.f, 0.f, 0.f};
    float mrow[4] = {-1e30f, -1e30f, -1e30f, -1e30f};
    float lrow[4] = {0.f, 0.f, 0.f, 0.f};

    const int jtmax = 2 * qt + 1;

    #define STAGE_KV(JT, BUF) do {                                              \
        const char* kt = kb + ((size_t)(JT) << 15);                             \
        char* ldsK = (char*)&KtL[(BUF)][0];                                     \
        _Pragma("unroll")                                                       \
        for (int i2 = 0; i2 < 8; ++i2) {                                        \
            int row = i2 * 4 + w;                                               \
            GLOAD_LDS16(kt + (row << 10) + (lsw ^ ((row & 7) << 4)),            \
                        ldsK + (row << 10));                                    \
        }                                                                       \
        const char* vtj = vtb + ((size_t)(JT) << 6);                            \
        char* ldsV = (char*)&VtL[(BUF)][0];                                     \
        _Pragma("unroll")                                                       \
        for (int i2 = 0; i2 < 8; ++i2) {                                        \
            int c0 = i2 * 256 + w * 64;                                         \
            int c  = c0 + lane;                                                 \
            GLOAD_LDS16(vtj + ((size_t)(c >> 2) << 11) + ((c & 3) << 4),        \
                        ldsV + c0 * 16);                                        \
        }                                                                       \
    } while (0)

    STAGE_KV(0, 0);
    __syncthreads();

    const int swz = (l15 & 7) << 4;

    for (int jt = 0; jt <= jtmax; ++jt) {
        const int cur = jt & 1;
        if (jt < jtmax) STAGE_KV(jt + 1, cur ^ 1);

        const char* Kc = (const char*)&KtL[cur][0];
        f32x4 sacc[2];
        sacc[0] = (f32x4){0.f, 0.f, 0.f, 0.f};
        sacc[1] = (f32x4){0.f, 0.f, 0.f, 0.f};
        #pragma unroll
        for (int ks = 0; ks < 16; ++ks) {
            int coloff = ((ks << 6) + (l4 << 4)) ^ swz;
            #pragma unroll
            for (int nf = 0; nf < 2; ++nf) {
                const bf16x8 kf = *(const bf16x8*)(Kc + ((nf * 16 + l15) << 10) + coloff);
                sacc[nf] = __builtin_amdgcn_mfma_f32_16x16x32_bf16(qf[ks], kf, sacc[nf], 0, 0, 0);
            }
        }

        const bool diag = (jt >= 2 * qt);
        float s[2][4];
        #pragma unroll
        for (int nf = 0; nf < 2; ++nf) {
            float bb_ = mbias[jt * 32 + nf * 16 + l15];
            #pragma unroll
            for (int r = 0; r < 4; ++r) {
                float val = sacc[nf][r] + bb_;
                if (diag) {
                    int gi = qt * 64 + w * 16 + l4 * 4 + r;
                    int gj = jt * 32 + nf * 16 + l15;
                    val = (gj <= gi) ? val : -3e38f;
                }
                s[nf][r] = val;
            }
        }
        float pm[4];
        #pragma unroll
        for (int r = 0; r < 4; ++r) {
            float mx = fmaxf(s[0][r], s[1][r]);
            mx = fmaxf(mx, __shfl_xor(mx, 1));
            mx = fmaxf(mx, __shfl_xor(mx, 2));
            mx = fmaxf(mx, __shfl_xor(mx, 4));
            mx = fmaxf(mx, __shfl_xor(mx, 8));
            pm[r] = mx;
        }
        bool need = false;
        #pragma unroll
        for (int r = 0; r < 4; ++r) need |= (pm[r] - mrow[r] > 8.0f);
        if (__any(need)) {
            #pragma unroll
            for (int r = 0; r < 4; ++r) {
                float mn = fmaxf(mrow[r], pm[r]);
                float corr = __expf(mrow[r] - mn);
                mrow[r] = mn;
                lrow[r] *= corr;
                #pragma unroll
                for (int n = 0; n < 32; ++n) oacc[n][r] *= corr;
            }
        }
        #pragma unroll
        for (int r = 0; r < 4; ++r) {
            float ls = 0.f;
            #pragma unroll
            for (int nf = 0; nf < 2; ++nf) {
                float p = __expf(s[nf][r] - mrow[r]);
                ls += p;
                Pw[w][l4 * 4 + r][nf * 16 + l15] = f2bf(p);
            }
            ls += __shfl_xor(ls, 1);
            ls += __shfl_xor(ls, 2);
            ls += __shfl_xor(ls, 4);
            ls += __shfl_xor(ls, 8);
            lrow[r] += ls;
        }

        const bf16x8 pa = *(const bf16x8*)&Pw[w][l15][l4 * 8];
        const char* Vc = (const char*)&VtL[cur][0];
        #pragma unroll
        for (int n = 0; n < 32; ++n) {
            const bf16x8 vb_ = *(const bf16x8*)(Vc + ((n * 16 + l15) << 6) + (l4 << 4));
            oacc[n] = __builtin_amdgcn_mfma_f32_16x16x32_bf16(pa, vb_, oacc[n], 0, 0, 0);
        }

        if (jt < jtmax) tile_barrier();
    }

    float inv[4];
    #pragma unroll
    for (int r = 0; r < 4; ++r) inv[r] = 1.0f / lrow[r];
    float* op = outp + ((size_t)(b * LL + qt * 64 + w * 16 + l4 * 4)) * DD + l15;
    #pragma unroll
    for (int n = 0; n < 32; ++n)
        #pragma unroll
        for (int r = 0; r < 4; ++r)
            op[(size_t)r * DD + n * 16] = fmaxf(oacc[n][r] * inv[r], 0.f);
    #undef STAGE_KV
}

extern "C" void kernel_launch(void* const* d_in, const int* in_sizes, int n_in,
                              void* d_out, int out_size, void* d_ws, size_t ws_size,
                              hipStream_t stream) {
    const float* x  = (const float*)d_in[0];
    const float* Wq = (const float*)d_in[1];
    const float* bq = (const float*)d_in[2];
    const float* Wk = (const float*)d_in[3];
    const float* bk = (const float*)d_in[4];
    const float* Wv = (const float*)d_in[5];
    const float* bv = (const float*)d_in[6];
    const int* mask = (const int*)d_in[7];

    unsigned short* qkv = (unsigned short*)d_ws;          // q|k|v bf16
    unsigned short* v   = qkv + 2 * MAT;
    unsigned short* vtp = qkv + 3 * MAT;                  // vt region
    unsigned short* Wb  = vtp;                            // parked, overwritten by vtrans
    unsigned short* xb  = (unsigned short*)d_out;         // x bf16 scratch
    float* out = (float*)d_out;

    cast_x<<<16384, 256, 0, stream>>>(x, xb);
    cast_w<<<768, 256, 0, stream>>>(Wq, Wk, Wv, Wb);
    qkv_proj3<<<dim3(1024, 3), 256, 0, stream>>>(xb, Wb, bq, bk, bv, qkv);
    vtrans<<<dim3(16, 8, 32), 256, 0, stream>>>(v, vtp);
    attn3<<<dim3(512), 256, 0, stream>>>(qkv, vtp, mask, out);
}